// Round 1
// baseline (199.690 us; speedup 1.0000x reference)
//
#include <hip/hip_runtime.h>

#define DIM 64

// CSR SpMM: out[i,:] = sum_{k in [indptr[i], indptr[i+1])} values[k] * x[indices[k],:]
// One 64-lane wave per row; lane = feature column.
__global__ __launch_bounds__(256) void spmm_row_wave_kernel(
    const float* __restrict__ x,
    const int*   __restrict__ indptr,
    const int*   __restrict__ indices,
    const float* __restrict__ values,
    float*       __restrict__ out,
    int n_nodes)
{
    const int wave = (int)((blockIdx.x * blockDim.x + threadIdx.x) >> 6);
    const int lane = (int)(threadIdx.x & 63);
    if (wave >= n_nodes) return;

    const int start = indptr[wave];
    const int end   = indptr[wave + 1];

    float acc = 0.0f;
    for (int k = start; k < end; ++k) {
        const int   col = indices[k];   // wave-uniform
        const float v   = values[k];    // wave-uniform
        acc += v * x[(size_t)col * DIM + lane];  // coalesced 256B row read
    }
    out[(size_t)wave * DIM + lane] = acc;        // coalesced 256B store
}

extern "C" void kernel_launch(void* const* d_in, const int* in_sizes, int n_in,
                              void* d_out, int out_size, void* d_ws, size_t ws_size,
                              hipStream_t stream) {
    const float* x       = (const float*)d_in[0];
    const int*   indptr  = (const int*)  d_in[1];
    const int*   indices = (const int*)  d_in[2];
    const float* values  = (const float*)d_in[3];
    float*       out     = (float*)d_out;

    const int n_nodes = in_sizes[1] - 1;   // indptr has N+1 entries

    const int threads = 256;               // 4 waves/block -> 4 rows/block
    const int rows_per_block = threads / 64;
    const int blocks = (n_nodes + rows_per_block - 1) / rows_per_block;

    spmm_row_wave_kernel<<<blocks, threads, 0, stream>>>(
        x, indptr, indices, values, out, n_nodes);
}

// Round 2
// 70.363 us; speedup vs baseline: 2.8380x; 2.8380x over previous
//
#include <hip/hip_runtime.h>

#define DIM 64

// CSR SpMM: out[i,:] = sum_{k in [indptr[i], indptr[i+1])} values[k] * x[indices[k],:]
// One 64-lane wave per row; lane = feature column.
// 8-deep software pipeline on the edge loop for gather MLP.
__global__ __launch_bounds__(256) void spmm_row_wave_kernel(
    const float* __restrict__ x,
    const int*   __restrict__ indptr,
    const int*   __restrict__ indices,
    const float* __restrict__ values,
    float*       __restrict__ out,
    int n_nodes)
{
    const int row  = (int)((blockIdx.x * blockDim.x + threadIdx.x) >> 6);
    const int lane = (int)(threadIdx.x & 63);
    if (row >= n_nodes) return;

    const int start = indptr[row];
    const int end   = indptr[row + 1];

    float acc = 0.0f;
    int k = start;

    // 8-deep pipeline: 8 independent gathers in flight per wave
    for (; k + 8 <= end; k += 8) {
        const int c0 = indices[k + 0];
        const int c1 = indices[k + 1];
        const int c2 = indices[k + 2];
        const int c3 = indices[k + 3];
        const int c4 = indices[k + 4];
        const int c5 = indices[k + 5];
        const int c6 = indices[k + 6];
        const int c7 = indices[k + 7];
        const float v0 = values[k + 0];
        const float v1 = values[k + 1];
        const float v2 = values[k + 2];
        const float v3 = values[k + 3];
        const float v4 = values[k + 4];
        const float v5 = values[k + 5];
        const float v6 = values[k + 6];
        const float v7 = values[k + 7];
        const float a0 = x[(size_t)c0 * DIM + lane];
        const float a1 = x[(size_t)c1 * DIM + lane];
        const float a2 = x[(size_t)c2 * DIM + lane];
        const float a3 = x[(size_t)c3 * DIM + lane];
        const float a4 = x[(size_t)c4 * DIM + lane];
        const float a5 = x[(size_t)c5 * DIM + lane];
        const float a6 = x[(size_t)c6 * DIM + lane];
        const float a7 = x[(size_t)c7 * DIM + lane];
        acc += v0 * a0;
        acc += v1 * a1;
        acc += v2 * a2;
        acc += v3 * a3;
        acc += v4 * a4;
        acc += v5 * a5;
        acc += v6 * a6;
        acc += v7 * a7;
    }

    // 4-deep tail
    if (k + 4 <= end) {
        const int c0 = indices[k + 0];
        const int c1 = indices[k + 1];
        const int c2 = indices[k + 2];
        const int c3 = indices[k + 3];
        const float v0 = values[k + 0];
        const float v1 = values[k + 1];
        const float v2 = values[k + 2];
        const float v3 = values[k + 3];
        const float a0 = x[(size_t)c0 * DIM + lane];
        const float a1 = x[(size_t)c1 * DIM + lane];
        const float a2 = x[(size_t)c2 * DIM + lane];
        const float a3 = x[(size_t)c3 * DIM + lane];
        acc += v0 * a0;
        acc += v1 * a1;
        acc += v2 * a2;
        acc += v3 * a3;
        k += 4;
    }

    // scalar tail (<= 3 iterations)
    for (; k < end; ++k) {
        acc += values[k] * x[(size_t)indices[k] * DIM + lane];
    }

    out[(size_t)row * DIM + lane] = acc;   // coalesced 256B store
}

extern "C" void kernel_launch(void* const* d_in, const int* in_sizes, int n_in,
                              void* d_out, int out_size, void* d_ws, size_t ws_size,
                              hipStream_t stream) {
    const float* x       = (const float*)d_in[0];
    const int*   indptr  = (const int*)  d_in[1];
    const int*   indices = (const int*)  d_in[2];
    const float* values  = (const float*)d_in[3];
    float*       out     = (float*)d_out;

    const int n_nodes = in_sizes[1] - 1;   // indptr has N+1 entries

    const int threads = 256;               // 4 waves/block -> 4 rows/block
    const int rows_per_block = threads / 64;
    const int blocks = (n_nodes + rows_per_block - 1) / rows_per_block;

    spmm_row_wave_kernel<<<blocks, threads, 0, stream>>>(
        x, indptr, indices, values, out, n_nodes);
}